// Round 4
// baseline (486.914 us; speedup 1.0000x reference)
//
#include <hip/hip_runtime.h>

#define DD 128
#define NNODES 50000
#define NEDGES 800000
#define BN_EPS 1e-5f
#define NBLK_SCAN ((NNODES + 255) / 256)   // 196

typedef float f32x4 __attribute__((ext_vector_type(4)));
typedef short bf16x8 __attribute__((ext_vector_type(8)));

__device__ __forceinline__ unsigned short f2bf(float f) {
    unsigned u = __float_as_uint(f);
    u = (u + 0x7FFFu + ((u >> 16) & 1u)) >> 16;   // RNE
    return (unsigned short)u;
}
__device__ __forceinline__ float bf2f(unsigned short s) {
    return __uint_as_float((unsigned)s << 16);
}
__device__ __forceinline__ unsigned packbf(float a, float b) {
    return (unsigned)f2bf(a) | ((unsigned)f2bf(b) << 16);
}
__device__ __forceinline__ float lo_bf(unsigned u) { return __uint_as_float(u << 16); }
__device__ __forceinline__ float hi_bf(unsigned u) { return __uint_as_float(u & 0xFFFF0000u); }

// ---------------------------------------------------------------------------
// CSR build: histogram -> two-level exclusive scan -> fill (atomic cursor).
// Edge payload packed as uint2 (col, w_bits): ONE scattered 8B store per edge.
// ---------------------------------------------------------------------------
__global__ __launch_bounds__(256) void hist_kernel(
    const int* __restrict__ row, int* __restrict__ deg, int nedges)
{
    int e = blockIdx.x * 256 + threadIdx.x;
    if (e < nedges) atomicAdd(&deg[row[e]], 1);
}

__global__ __launch_bounds__(256) void scan1_kernel(
    const int* __restrict__ deg, int* __restrict__ excl, int* __restrict__ bsum, int n)
{
    __shared__ int buf[256];
    int i = blockIdx.x * 256 + threadIdx.x;
    int v = (i < n) ? deg[i] : 0;
    buf[threadIdx.x] = v;
    __syncthreads();
#pragma unroll
    for (int off = 1; off < 256; off <<= 1) {
        int t = (threadIdx.x >= off) ? buf[threadIdx.x - off] : 0;
        __syncthreads();
        buf[threadIdx.x] += t;
        __syncthreads();
    }
    if (i < n) excl[i] = buf[threadIdx.x] - v;
    if (threadIdx.x == 255) bsum[blockIdx.x] = buf[255];
}

__global__ __launch_bounds__(256) void scan2_kernel(
    int* __restrict__ bsum, int* __restrict__ boff, int nblk)
{
    __shared__ int buf[256];
    int v = (threadIdx.x < nblk) ? bsum[threadIdx.x] : 0;
    buf[threadIdx.x] = v;
    __syncthreads();
#pragma unroll
    for (int off = 1; off < 256; off <<= 1) {
        int t = (threadIdx.x >= off) ? buf[threadIdx.x - off] : 0;
        __syncthreads();
        buf[threadIdx.x] += t;
        __syncthreads();
    }
    if (threadIdx.x < nblk) boff[threadIdx.x] = buf[threadIdx.x] - v;
}

__global__ __launch_bounds__(256) void scan3_kernel(
    int* __restrict__ rowptr, const int* __restrict__ boff,
    int* __restrict__ cursor, int n)
{
    int i = blockIdx.x * 256 + threadIdx.x;
    if (i < n) {
        int v = rowptr[i] + boff[blockIdx.x];
        rowptr[i] = v;
        cursor[i] = v;
    }
    if (i == 0) rowptr[n] = NEDGES;
}

__global__ __launch_bounds__(256) void csr_fill_kernel(
    const int* __restrict__ row, const int* __restrict__ col,
    const float* __restrict__ ew, int* __restrict__ cursor,
    uint2* __restrict__ cedge, int nedges)
{
    int e = blockIdx.x * 256 + threadIdx.x;
    if (e < nedges) {
        int r = row[e];
        int p = atomicAdd(&cursor[r], 1);
        cedge[p] = make_uint2((unsigned)col[e], __float_as_uint(ew[e]));
    }
}

// ---------------------------------------------------------------------------
// Converters
// ---------------------------------------------------------------------------
__global__ __launch_bounds__(256) void conv_x16_kernel(
    const float* __restrict__ x, unsigned* __restrict__ h16u, int npairs)
{
    int stride = gridDim.x * 256;
    for (int i = blockIdx.x * 256 + threadIdx.x; i < npairs; i += stride) {
        float2 v = ((const float2*)x)[i];
        h16u[i] = packbf(v.x, v.y);
    }
}

// Wf: MFMA-fragment-ordered [li][ks 0..7][nt 0..7][lane 0..63][i 0..7] bf16
// value = B[k][n], k = ks*32 + (lane>>4)*8 + i (k<128 -> W, else SW), n = nt*16 + (lane&15)
__global__ __launch_bounds__(256) void conv_wf_kernel(
    const float* __restrict__ W, const float* __restrict__ SW,
    unsigned short* __restrict__ Wf)
{
    int t = blockIdx.x * 256 + threadIdx.x;     // 12288 total
    if (t >= 3 * 8 * 8 * 64) return;
    int lane = t & 63;
    int nt   = (t >> 6) & 7;
    int ks   = (t >> 9) & 7;
    int li   = t >> 12;                          // 0..2
    const int lmap[3] = {0, 2, 5};
    int l = lmap[li];
    int n = nt * 16 + (lane & 15);
    unsigned short* dst = Wf + (((size_t)li * 64 + ks * 8 + nt) * 64 + lane) * 8;
#pragma unroll
    for (int i = 0; i < 8; ++i) {
        int k = ks * 32 + (lane >> 4) * 8 + i;
        float v = (k < 128) ? W[((size_t)l * 128 + k) * 128 + n]
                            : SW[((size_t)l * 128 + (k - 128)) * 128 + n];
        dst[i] = f2bf(v);
    }
}

// ---------------------------------------------------------------------------
// Fused per-layer kernel:
//   phase 1: CSR gather of this block's 64 rows -> LDS A-tile k-chunks 0..15
//            (fp32 accumulate in regs, packed bf16 store; wave w owns 16 rows)
//   phase 2: stage own h rows -> LDS k-chunks 16..31
//   phase 3: MFMA  C = [agg|h] @ [W;SW]  (K=256)
//   phase 4: BN + relu + residual (h row re-read from LDS), write h_out bf16
//            (+ f32 out for the last layer)
// h is ping-pong buffered: gather reads h_in (complete from prior layer),
// epilogue writes h_out -> no cross-block RAW hazard, dispatch-order safe.
// ---------------------------------------------------------------------------
__global__ __launch_bounds__(256) void gemm_fused_kernel(
    const unsigned* __restrict__ h_in,       // [n][64] packed bf16 pairs
    unsigned short* __restrict__ h_out,      // [n][128] bf16
    const int* __restrict__ rowptr,
    const uint2* __restrict__ cedge,
    const unsigned short* __restrict__ Wf,   // this layer's 32768 ushorts
    const float* __restrict__ bl, const float* __restrict__ gammal,
    const float* __restrict__ betal, const float* __restrict__ rmeanl,
    const float* __restrict__ rvarl,
    float* __restrict__ outf, int n, int write_f32)
{
    __shared__ __align__(16) unsigned short As[64 * 256];   // 32 KB
    const int tid  = threadIdx.x;
    const int lane = tid & 63;
    const int wid  = tid >> 6;
    const int brow = blockIdx.x * 64;

    // ---- B prefetch (issued first; consumed after the barrier) ----
    bf16x8 bfr[8][2];
#pragma unroll
    for (int ks = 0; ks < 8; ++ks)
#pragma unroll
        for (int nt2 = 0; nt2 < 2; ++nt2) {
            int nt = wid * 2 + nt2;
            bfr[ks][nt2] = *(const bf16x8*)(Wf + ((size_t)(ks * 8 + nt) * 64 + lane) * 8);
        }

    // ---- phase 1: gather 16 rows per wave into LDS chunks 0..15 ----
    {
        const int chunk = lane >> 2;          // 16B chunk 0..15
        const int coff  = (lane & 3) * 2;     // bf16 offset within chunk
        for (int i = 0; i < 16; ++i) {
            const int r = wid * 16 + i;
            const int node = brow + r;
            if (node >= n) break;             // wave-uniform
            const int beg = rowptr[node];
            const int end = rowptr[node + 1];
            float ax = 0.f, ay = 0.f;
            int j = beg;
            for (; j + 4 <= end; j += 4) {
                uint2 e0 = cedge[j], e1 = cedge[j+1], e2 = cedge[j+2], e3 = cedge[j+3];
                unsigned u0 = h_in[(size_t)e0.x * 64 + lane];
                unsigned u1 = h_in[(size_t)e1.x * 64 + lane];
                unsigned u2 = h_in[(size_t)e2.x * 64 + lane];
                unsigned u3 = h_in[(size_t)e3.x * 64 + lane];
                float w0 = __uint_as_float(e0.y), w1 = __uint_as_float(e1.y);
                float w2 = __uint_as_float(e2.y), w3 = __uint_as_float(e3.y);
                ax += w0 * lo_bf(u0) + w1 * lo_bf(u1) + w2 * lo_bf(u2) + w3 * lo_bf(u3);
                ay += w0 * hi_bf(u0) + w1 * hi_bf(u1) + w2 * hi_bf(u2) + w3 * hi_bf(u3);
            }
            for (; j < end; ++j) {
                uint2 e = cedge[j];
                unsigned u = h_in[(size_t)e.x * 64 + lane];
                float w = __uint_as_float(e.y);
                ax += w * lo_bf(u);
                ay += w * hi_bf(u);
            }
            *(unsigned*)(&As[r * 256 + ((chunk ^ (r & 7)) * 8) + coff]) = packbf(ax, ay);
        }
    }

    // ---- phase 2: stage own h rows into LDS chunks 16..31 ----
#pragma unroll
    for (int it = 0; it < 4; ++it) {
        int id   = tid + it * 256;         // 0..1023
        int r    = id >> 4;                // 0..63
        int kc16 = id & 15;                // 0..15
        int grow = brow + r;
        uint4 v = make_uint4(0, 0, 0, 0);
        if (grow < n) v = *(const uint4*)(h_in + (size_t)grow * 64 + kc16 * 4);
        int chunk = 16 + kc16;
        *(uint4*)(&As[r * 256 + ((chunk ^ (r & 7)) * 8)]) = v;
    }
    __syncthreads();

    // ---- phase 3: K loop, 8 steps of K=32, 4 m-tiles, 2 n-tiles ----
    f32x4 acc[4][2];
#pragma unroll
    for (int i = 0; i < 4; ++i)
#pragma unroll
        for (int j = 0; j < 2; ++j)
            acc[i][j] = (f32x4){0.f, 0.f, 0.f, 0.f};

#pragma unroll
    for (int ks = 0; ks < 8; ++ks) {
#pragma unroll
        for (int mt = 0; mt < 4; ++mt) {
            int m   = mt * 16 + (lane & 15);
            int kc  = ks * 4 + (lane >> 4);
            int kcs = kc ^ (m & 7);
            bf16x8 afr = *(const bf16x8*)(&As[m * 256 + kcs * 8]);
            acc[mt][0] = __builtin_amdgcn_mfma_f32_16x16x32_bf16(afr, bfr[ks][0], acc[mt][0], 0, 0, 0);
            acc[mt][1] = __builtin_amdgcn_mfma_f32_16x16x32_bf16(afr, bfr[ks][1], acc[mt][1], 0, 0, 0);
        }
    }

    // ---- phase 4: BN + relu + residual(LDS) ----
#pragma unroll
    for (int nt2 = 0; nt2 < 2; ++nt2) {
        const int gcol = wid * 32 + nt2 * 16 + (lane & 15);
        const float sc = gammal[gcol] * __frsqrt_rn(rvarl[gcol] + BN_EPS);
        const float sh = (bl[gcol] - rmeanl[gcol]) * sc + betal[gcol];
        const int kc_res = 16 + (gcol >> 3);
        const int ko_res = gcol & 7;
#pragma unroll
        for (int mt = 0; mt < 4; ++mt) {
#pragma unroll
            for (int r = 0; r < 4; ++r) {
                int m = mt * 16 + (lane >> 4) * 4 + r;
                int grow = brow + m;
                if (grow < n) {
                    float res = bf2f(As[m * 256 + (kc_res ^ (m & 7)) * 8 + ko_res]);
                    float t = acc[mt][nt2][r] * sc + sh;
                    float o = res + (t > 0.f ? t : 0.f);
                    h_out[(size_t)grow * DD + gcol] = f2bf(o);
                    if (write_f32) outf[(size_t)grow * DD + gcol] = o;
                }
            }
        }
    }
}

extern "C" void kernel_launch(void* const* d_in, const int* in_sizes, int n_in,
                              void* d_out, int out_size, void* d_ws, size_t ws_size,
                              hipStream_t stream) {
    const float* x     = (const float*)d_in[0];
    const int*   row   = (const int*)  d_in[1];
    const int*   col   = (const int*)  d_in[2];
    const float* ew    = (const float*)d_in[3];
    const float* W     = (const float*)d_in[4];
    const float* SW    = (const float*)d_in[5];
    const float* b     = (const float*)d_in[6];
    const float* gamma = (const float*)d_in[7];
    const float* beta  = (const float*)d_in[8];
    const float* rmean = (const float*)d_in[9];
    const float* rvar  = (const float*)d_in[10];

    float* out = (float*)d_out;

    // workspace layout
    char* ws = (char*)d_ws;
    unsigned*       hA     = (unsigned*)ws;                              // 12.8 MB
    unsigned*       hB     = (unsigned*)(ws + 12800000);                 // 12.8 MB
    unsigned short* Wf     = (unsigned short*)(ws + 25600000);           // 196608 B
    int*   rowptr = (int*)(ws + 25796608);                               // N+1
    int*   cursor = rowptr + NNODES + 1;
    int*   deg    = cursor + NNODES;
    int*   bsum   = deg + NNODES;
    int*   boff   = bsum + 256;
    uint2* cedge  = (uint2*)(ws + 26400000);                             // 6.4 MB (16B-aligned)

    const int egrid = (NEDGES + 255) / 256;   // 3125

    // ---- build CSR once (row/col/ew are layer-invariant) ----
    hipMemsetAsync(deg, 0, NNODES * sizeof(int), stream);
    hist_kernel<<<egrid, 256, 0, stream>>>(row, deg, NEDGES);
    scan1_kernel<<<NBLK_SCAN, 256, 0, stream>>>(deg, rowptr, bsum, NNODES);
    scan2_kernel<<<1, 256, 0, stream>>>(bsum, boff, NBLK_SCAN);
    scan3_kernel<<<NBLK_SCAN, 256, 0, stream>>>(rowptr, boff, cursor, NNODES);
    csr_fill_kernel<<<egrid, 256, 0, stream>>>(row, col, ew, cursor, cedge, NEDGES);

    // ---- converts ----
    conv_x16_kernel<<<2048, 256, 0, stream>>>(x, hA, NNODES * 64);
    conv_wf_kernel<<<48, 256, 0, stream>>>(W, SW, Wf);

    // Only layers 0, 2, 5 are live (inner branch layers all consume the
    // branch input, so only each branch's last layer reaches the output).
    const int mgrid = (NNODES + 63) / 64;     // 782

    const unsigned* hin = hA;
    unsigned* hout = hB;
    for (int li = 0; li < 3; ++li) {
        const int l = (li == 0) ? 0 : (li == 1) ? 2 : 5;
        gemm_fused_kernel<<<mgrid, 256, 0, stream>>>(
            hin, (unsigned short*)hout, rowptr, cedge,
            Wf + (size_t)li * 32768,
            b + l * DD, gamma + l * DD, beta + l * DD, rmean + l * DD, rvar + l * DD,
            out, NNODES, li == 2 ? 1 : 0);
        const unsigned* t = hin; hin = (const unsigned*)hout; hout = (unsigned*)t;
    }
}

// Round 5
// 257.684 us; speedup vs baseline: 1.8896x; 1.8896x over previous
//
#include <hip/hip_runtime.h>

#define DD 128
#define NNODES 50000
#define NEDGES 800000
#define BN_EPS 1e-5f
#define NBLK_SCAN ((NNODES + 255) / 256)   // 196

typedef float f32x4 __attribute__((ext_vector_type(4)));
typedef short bf16x8 __attribute__((ext_vector_type(8)));

__device__ __forceinline__ unsigned short f2bf(float f) {
    unsigned u = __float_as_uint(f);
    u = (u + 0x7FFFu + ((u >> 16) & 1u)) >> 16;   // RNE
    return (unsigned short)u;
}
__device__ __forceinline__ float bf2f(unsigned short s) {
    return __uint_as_float((unsigned)s << 16);
}
__device__ __forceinline__ unsigned packbf(float a, float b) {
    return (unsigned)f2bf(a) | ((unsigned)f2bf(b) << 16);
}
__device__ __forceinline__ float lo_bf(unsigned u) { return __uint_as_float(u << 16); }
__device__ __forceinline__ float hi_bf(unsigned u) { return __uint_as_float(u & 0xFFFF0000u); }

// ---------------------------------------------------------------------------
// CSR build: histogram -> two-level exclusive scan -> fill (atomic cursor).
// Edge payload packed into 4 BYTES: (w_bf16 << 16) | col  (col < 65536).
// One 4B scattered store per edge; a row's ~16 edges span ~one 64B line.
// ---------------------------------------------------------------------------
__global__ __launch_bounds__(256) void hist_kernel(
    const int* __restrict__ row, int* __restrict__ deg, int nedges)
{
    int e = blockIdx.x * 256 + threadIdx.x;
    if (e < nedges) atomicAdd(&deg[row[e]], 1);
}

__global__ __launch_bounds__(256) void scan1_kernel(
    const int* __restrict__ deg, int* __restrict__ excl, int* __restrict__ bsum, int n)
{
    __shared__ int buf[256];
    int i = blockIdx.x * 256 + threadIdx.x;
    int v = (i < n) ? deg[i] : 0;
    buf[threadIdx.x] = v;
    __syncthreads();
#pragma unroll
    for (int off = 1; off < 256; off <<= 1) {
        int t = (threadIdx.x >= off) ? buf[threadIdx.x - off] : 0;
        __syncthreads();
        buf[threadIdx.x] += t;
        __syncthreads();
    }
    if (i < n) excl[i] = buf[threadIdx.x] - v;
    if (threadIdx.x == 255) bsum[blockIdx.x] = buf[255];
}

__global__ __launch_bounds__(256) void scan2_kernel(
    int* __restrict__ bsum, int* __restrict__ boff, int nblk)
{
    __shared__ int buf[256];
    int v = (threadIdx.x < nblk) ? bsum[threadIdx.x] : 0;
    buf[threadIdx.x] = v;
    __syncthreads();
#pragma unroll
    for (int off = 1; off < 256; off <<= 1) {
        int t = (threadIdx.x >= off) ? buf[threadIdx.x - off] : 0;
        __syncthreads();
        buf[threadIdx.x] += t;
        __syncthreads();
    }
    if (threadIdx.x < nblk) boff[threadIdx.x] = buf[threadIdx.x] - v;
}

__global__ __launch_bounds__(256) void scan3_kernel(
    int* __restrict__ rowptr, const int* __restrict__ boff,
    int* __restrict__ cursor, int n)
{
    int i = blockIdx.x * 256 + threadIdx.x;
    if (i < n) {
        int v = rowptr[i] + boff[blockIdx.x];
        rowptr[i] = v;
        cursor[i] = v;
    }
    if (i == 0) rowptr[n] = NEDGES;
}

__global__ __launch_bounds__(256) void csr_fill_kernel(
    const int* __restrict__ row, const int* __restrict__ col,
    const float* __restrict__ ew, int* __restrict__ cursor,
    unsigned* __restrict__ cedge, int nedges)
{
    int e = blockIdx.x * 256 + threadIdx.x;
    if (e < nedges) {
        int r = row[e];
        int p = atomicAdd(&cursor[r], 1);
        cedge[p] = (unsigned)col[e] | ((unsigned)f2bf(ew[e]) << 16);
    }
}

// ---------------------------------------------------------------------------
// Converters
// ---------------------------------------------------------------------------
__global__ __launch_bounds__(256) void conv_x16_kernel(
    const float* __restrict__ x, unsigned* __restrict__ h16u, int npairs)
{
    int stride = gridDim.x * 256;
    for (int i = blockIdx.x * 256 + threadIdx.x; i < npairs; i += stride) {
        float2 v = ((const float2*)x)[i];
        h16u[i] = packbf(v.x, v.y);
    }
}

// Wf: MFMA-fragment-ordered [li][ks 0..7][nt 0..7][lane 0..63][i 0..7] bf16
// value = B[k][n], k = ks*32 + (lane>>4)*8 + i (k<128 -> W, else SW), n = nt*16 + (lane&15)
__global__ __launch_bounds__(256) void conv_wf_kernel(
    const float* __restrict__ W, const float* __restrict__ SW,
    unsigned short* __restrict__ Wf)
{
    int t = blockIdx.x * 256 + threadIdx.x;     // 12288 total
    if (t >= 3 * 8 * 8 * 64) return;
    int lane = t & 63;
    int nt   = (t >> 6) & 7;
    int ks   = (t >> 9) & 7;
    int li   = t >> 12;                          // 0..2
    const int lmap[3] = {0, 2, 5};
    int l = lmap[li];
    int n = nt * 16 + (lane & 15);
    unsigned short* dst = Wf + (((size_t)li * 64 + ks * 8 + nt) * 64 + lane) * 8;
#pragma unroll
    for (int i = 0; i < 8; ++i) {
        int k = ks * 32 + (lane >> 4) * 8 + i;
        float v = (k < 128) ? W[((size_t)l * 128 + k) * 128 + n]
                            : SW[((size_t)l * 128 + (k - 128)) * 128 + n];
        dst[i] = f2bf(v);
    }
}

// ---------------------------------------------------------------------------
// CSR gather: one wave per node, two 32-lane halves walk even/odd edges of
// the SAME node (trip counts differ by <=1). Lane owns 4 bf16 cols (8B load).
// x4 unroll -> 8 row-reads in flight per wave. Combine via shfl_xor(32).
// ---------------------------------------------------------------------------
__global__ __launch_bounds__(256) void spmm_gather16_kernel(
    const uint2* __restrict__ h2, const int* __restrict__ rowptr,
    const unsigned* __restrict__ ce, uint2* __restrict__ agg2, int n)
{
    int node = blockIdx.x * 4 + (threadIdx.x >> 6);
    if (node >= n) return;
    const int lane = threadIdx.x & 63;
    const int half = lane >> 5;
    const int l32  = lane & 31;
    const int beg = rowptr[node];
    const int end = rowptr[node + 1];

    float a0 = 0.f, a1 = 0.f, a2 = 0.f, a3 = 0.f;
    int j = beg + half;
    for (; j + 6 < end; j += 8) {
        unsigned e0 = ce[j], e1 = ce[j+2], e2 = ce[j+4], e3 = ce[j+6];
        uint2 v0 = h2[(size_t)(e0 & 0xFFFFu) * 32 + l32];
        uint2 v1 = h2[(size_t)(e1 & 0xFFFFu) * 32 + l32];
        uint2 v2 = h2[(size_t)(e2 & 0xFFFFu) * 32 + l32];
        uint2 v3 = h2[(size_t)(e3 & 0xFFFFu) * 32 + l32];
        float w0 = bf2f((unsigned short)(e0 >> 16));
        float w1 = bf2f((unsigned short)(e1 >> 16));
        float w2 = bf2f((unsigned short)(e2 >> 16));
        float w3 = bf2f((unsigned short)(e3 >> 16));
        a0 += w0*lo_bf(v0.x) + w1*lo_bf(v1.x) + w2*lo_bf(v2.x) + w3*lo_bf(v3.x);
        a1 += w0*hi_bf(v0.x) + w1*hi_bf(v1.x) + w2*hi_bf(v2.x) + w3*hi_bf(v3.x);
        a2 += w0*lo_bf(v0.y) + w1*lo_bf(v1.y) + w2*lo_bf(v2.y) + w3*lo_bf(v3.y);
        a3 += w0*hi_bf(v0.y) + w1*hi_bf(v1.y) + w2*hi_bf(v2.y) + w3*hi_bf(v3.y);
    }
    for (; j < end; j += 2) {
        unsigned e = ce[j];
        uint2 v = h2[(size_t)(e & 0xFFFFu) * 32 + l32];
        float w = bf2f((unsigned short)(e >> 16));
        a0 += w * lo_bf(v.x); a1 += w * hi_bf(v.x);
        a2 += w * lo_bf(v.y); a3 += w * hi_bf(v.y);
    }
    a0 += __shfl_xor(a0, 32);
    a1 += __shfl_xor(a1, 32);
    a2 += __shfl_xor(a2, 32);
    a3 += __shfl_xor(a3, 32);
    if (half == 0)
        agg2[(size_t)node * 32 + l32] = make_uint2(packbf(a0, a1), packbf(a2, a3));
}

// ---------------------------------------------------------------------------
// MFMA GEMM: C = [agg|h](N x 256) @ [W;SW](256 x 128), then BN+relu+residual.
// Block: 256 thr (4 waves), BM=64 rows. Wave w owns cols [32w, 32w+32).
// A staged in LDS (bf16, XOR chunk-swizzle); B prefetched from frag-ordered Wf.
// Residual h row read back from the LDS tile. h16 updated in-place (each
// block writes only rows it staged). Last layer also writes f32 out.
// ---------------------------------------------------------------------------
__global__ __launch_bounds__(256) void gemm_mfma_kernel(
    unsigned short* __restrict__ h16,        // [n][128] bf16, in-place update
    const unsigned short* __restrict__ agg16,
    const unsigned short* __restrict__ Wf,   // this layer's 32768 ushorts
    const float* __restrict__ bl, const float* __restrict__ gammal,
    const float* __restrict__ betal, const float* __restrict__ rmeanl,
    const float* __restrict__ rvarl,
    float* __restrict__ outf, int n, int write_f32)
{
    __shared__ __align__(16) unsigned short As[64 * 256];   // 32 KB
    const int tid  = threadIdx.x;
    const int lane = tid & 63;
    const int wid  = tid >> 6;
    const int brow = blockIdx.x * 64;

    // ---- B prefetch: 16 frags/wave (8 ksteps x 2 ntiles) ----
    bf16x8 bfr[8][2];
#pragma unroll
    for (int ks = 0; ks < 8; ++ks)
#pragma unroll
        for (int nt2 = 0; nt2 < 2; ++nt2) {
            int nt = wid * 2 + nt2;
            bfr[ks][nt2] = *(const bf16x8*)(Wf + ((size_t)(ks * 8 + nt) * 64 + lane) * 8);
        }

    // ---- stage A tile: 64 rows x 256 bf16 (k<128: agg, k>=128: h) ----
#pragma unroll
    for (int it = 0; it < 8; ++it) {
        int id = tid + it * 256;          // 0..2047
        int r  = id >> 5;                 // 0..63
        int kc = id & 31;                 // 16B chunk (8 bf16)
        int grow = brow + r;
        uint4 v = make_uint4(0, 0, 0, 0);
        if (grow < n) {
            const unsigned short* src = (kc < 16)
                ? (agg16 + (size_t)grow * DD + kc * 8)
                : (h16   + (size_t)grow * DD + (kc - 16) * 8);
            v = *(const uint4*)src;
        }
        int kcs = kc ^ (r & 7);
        *(uint4*)(&As[r * 256 + kcs * 8]) = v;
    }
    __syncthreads();

    // ---- K loop: 8 steps of K=32, 4 m-tiles, 2 n-tiles ----
    f32x4 acc[4][2];
#pragma unroll
    for (int i = 0; i < 4; ++i)
#pragma unroll
        for (int j = 0; j < 2; ++j)
            acc[i][j] = (f32x4){0.f, 0.f, 0.f, 0.f};

#pragma unroll
    for (int ks = 0; ks < 8; ++ks) {
#pragma unroll
        for (int mt = 0; mt < 4; ++mt) {
            int m   = mt * 16 + (lane & 15);
            int kc  = ks * 4 + (lane >> 4);
            int kcs = kc ^ (m & 7);
            bf16x8 afr = *(const bf16x8*)(&As[m * 256 + kcs * 8]);
            acc[mt][0] = __builtin_amdgcn_mfma_f32_16x16x32_bf16(afr, bfr[ks][0], acc[mt][0], 0, 0, 0);
            acc[mt][1] = __builtin_amdgcn_mfma_f32_16x16x32_bf16(afr, bfr[ks][1], acc[mt][1], 0, 0, 0);
        }
    }

    // ---- epilogue: BN + relu + residual(LDS) ----
#pragma unroll
    for (int nt2 = 0; nt2 < 2; ++nt2) {
        const int gcol = wid * 32 + nt2 * 16 + (lane & 15);
        const float sc = gammal[gcol] * __frsqrt_rn(rvarl[gcol] + BN_EPS);
        const float sh = (bl[gcol] - rmeanl[gcol]) * sc + betal[gcol];
        const int kc_res = 16 + (gcol >> 3);
        const int ko_res = gcol & 7;
#pragma unroll
        for (int mt = 0; mt < 4; ++mt) {
#pragma unroll
            for (int r = 0; r < 4; ++r) {
                int m = mt * 16 + (lane >> 4) * 4 + r;
                int grow = brow + m;
                if (grow < n) {
                    float res = bf2f(As[m * 256 + (kc_res ^ (m & 7)) * 8 + ko_res]);
                    float t = acc[mt][nt2][r] * sc + sh;
                    float o = res + (t > 0.f ? t : 0.f);
                    h16[(size_t)grow * DD + gcol] = f2bf(o);
                    if (write_f32) outf[(size_t)grow * DD + gcol] = o;
                }
            }
        }
    }
}

extern "C" void kernel_launch(void* const* d_in, const int* in_sizes, int n_in,
                              void* d_out, int out_size, void* d_ws, size_t ws_size,
                              hipStream_t stream) {
    const float* x     = (const float*)d_in[0];
    const int*   row   = (const int*)  d_in[1];
    const int*   col   = (const int*)  d_in[2];
    const float* ew    = (const float*)d_in[3];
    const float* W     = (const float*)d_in[4];
    const float* SW    = (const float*)d_in[5];
    const float* b     = (const float*)d_in[6];
    const float* gamma = (const float*)d_in[7];
    const float* beta  = (const float*)d_in[8];
    const float* rmean = (const float*)d_in[9];
    const float* rvar  = (const float*)d_in[10];

    float* out = (float*)d_out;

    // workspace layout
    char* ws = (char*)d_ws;
    unsigned*       agg16u = (unsigned*)ws;                              // 12.8 MB
    unsigned*       h16u   = (unsigned*)(ws + 12800000);                 // 12.8 MB
    unsigned short* Wf     = (unsigned short*)(ws + 25600000);           // 196608 B
    int*   rowptr = (int*)(ws + 25796608);                               // N+1
    int*   cursor = rowptr + NNODES + 1;
    int*   deg    = cursor + NNODES;
    int*   bsum   = deg + NNODES;
    int*   boff   = bsum + 256;
    unsigned* cedge = (unsigned*)(ws + 26400000);                        // 3.2 MB

    const int egrid = (NEDGES + 255) / 256;   // 3125

    // ---- build CSR once (row/col/ew are layer-invariant) ----
    hipMemsetAsync(deg, 0, NNODES * sizeof(int), stream);
    hist_kernel<<<egrid, 256, 0, stream>>>(row, deg, NEDGES);
    scan1_kernel<<<NBLK_SCAN, 256, 0, stream>>>(deg, rowptr, bsum, NNODES);
    scan2_kernel<<<1, 256, 0, stream>>>(bsum, boff, NBLK_SCAN);
    scan3_kernel<<<NBLK_SCAN, 256, 0, stream>>>(rowptr, boff, cursor, NNODES);
    csr_fill_kernel<<<egrid, 256, 0, stream>>>(row, col, ew, cursor, cedge, NEDGES);

    // ---- converts ----
    conv_x16_kernel<<<2048, 256, 0, stream>>>(x, h16u, NNODES * 64);
    conv_wf_kernel<<<48, 256, 0, stream>>>(W, SW, Wf);

    // Only layers 0, 2, 5 are live (inner branch layers all consume the
    // branch input, so only each branch's last layer reaches the output).
    const int ggrid = (NNODES + 3) / 4;       // 12500
    const int mgrid = (NNODES + 63) / 64;     // 782

    for (int li = 0; li < 3; ++li) {
        const int l = (li == 0) ? 0 : (li == 1) ? 2 : 5;
        spmm_gather16_kernel<<<ggrid, 256, 0, stream>>>(
            (const uint2*)h16u, rowptr, cedge, (uint2*)agg16u, NNODES);
        gemm_mfma_kernel<<<mgrid, 256, 0, stream>>>(
            (unsigned short*)h16u, (const unsigned short*)agg16u,
            Wf + (size_t)li * 32768,
            b + l * DD, gamma + l * DD, beta + l * DD, rmean + l * DD, rvar + l * DD,
            out, NNODES, li == 2 ? 1 : 0);
    }
}

// Round 6
// 226.407 us; speedup vs baseline: 2.1506x; 1.1381x over previous
//
#include <hip/hip_runtime.h>

#define DD 128
#define NNODES 50000
#define NEDGES 800000
#define BN_EPS 1e-5f
#define NBLK_SCAN ((NNODES + 255) / 256)   // 196
#define NB1 ((NEDGES + 4095) / 4096)       // 196 pass-1 blocks
#define NGROUPS ((NNODES + 255) / 256)     // 196 row-groups (256 rows each)
#define HIST_BLOCKS ((NEDGES + 255) / 256) // 3125

typedef float f32x4 __attribute__((ext_vector_type(4)));
typedef short bf16x8 __attribute__((ext_vector_type(8)));

__device__ __forceinline__ unsigned short f2bf(float f) {
    unsigned u = __float_as_uint(f);
    u = (u + 0x7FFFu + ((u >> 16) & 1u)) >> 16;   // RNE
    return (unsigned short)u;
}
__device__ __forceinline__ float bf2f(unsigned short s) {
    return __uint_as_float((unsigned)s << 16);
}
__device__ __forceinline__ unsigned packbf(float a, float b) {
    return (unsigned)f2bf(a) | ((unsigned)f2bf(b) << 16);
}
__device__ __forceinline__ float lo_bf(unsigned u) { return __uint_as_float(u << 16); }
__device__ __forceinline__ float hi_bf(unsigned u) { return __uint_as_float(u & 0xFFFF0000u); }

// ---------------------------------------------------------------------------
// hist (deg) + x->bf16 convert, fused into one launch (independent work).
// ---------------------------------------------------------------------------
__global__ __launch_bounds__(256) void hist_convx_kernel(
    const int* __restrict__ row, int* __restrict__ deg,
    const float* __restrict__ x, unsigned* __restrict__ h16u,
    int nedges, int npairs)
{
    int bid = blockIdx.x;
    if (bid < HIST_BLOCKS) {
        int e = bid * 256 + threadIdx.x;
        if (e < nedges) atomicAdd(&deg[row[e]], 1);
    } else {
        int stride = (gridDim.x - HIST_BLOCKS) * 256;
        for (int i = (bid - HIST_BLOCKS) * 256 + threadIdx.x; i < npairs; i += stride) {
            float2 v = ((const float2*)x)[i];
            h16u[i] = packbf(v.x, v.y);
        }
    }
}

// ---------------------------------------------------------------------------
// scan1 (+ conv_wf folded into extra blocks)
// Wf: MFMA-fragment-ordered [li][ks][nt][lane][i] bf16,
// value = B[k][n], k = ks*32+(lane>>4)*8+i (k<128 -> W else SW), n = nt*16+(lane&15)
// ---------------------------------------------------------------------------
__global__ __launch_bounds__(256) void scan1_convwf_kernel(
    const int* __restrict__ deg, int* __restrict__ excl, int* __restrict__ bsum,
    const float* __restrict__ W, const float* __restrict__ SW,
    unsigned short* __restrict__ Wf, int n)
{
    if (blockIdx.x >= NBLK_SCAN) {
        int t = (blockIdx.x - NBLK_SCAN) * 256 + threadIdx.x;   // 12288 total
        if (t < 3 * 8 * 8 * 64) {
            int lane = t & 63;
            int nt   = (t >> 6) & 7;
            int ks   = (t >> 9) & 7;
            int li   = t >> 12;
            const int lmap[3] = {0, 2, 5};
            int l = lmap[li];
            int nn = nt * 16 + (lane & 15);
            unsigned short* dst = Wf + (((size_t)li * 64 + ks * 8 + nt) * 64 + lane) * 8;
#pragma unroll
            for (int i = 0; i < 8; ++i) {
                int k = ks * 32 + (lane >> 4) * 8 + i;
                float v = (k < 128) ? W[((size_t)l * 128 + k) * 128 + nn]
                                    : SW[((size_t)l * 128 + (k - 128)) * 128 + nn];
                dst[i] = f2bf(v);
            }
        }
        return;
    }
    __shared__ int buf[256];
    int i = blockIdx.x * 256 + threadIdx.x;
    int v = (i < n) ? deg[i] : 0;
    buf[threadIdx.x] = v;
    __syncthreads();
#pragma unroll
    for (int off = 1; off < 256; off <<= 1) {
        int t = (threadIdx.x >= off) ? buf[threadIdx.x - off] : 0;
        __syncthreads();
        buf[threadIdx.x] += t;
        __syncthreads();
    }
    if (i < n) excl[i] = buf[threadIdx.x] - v;
    if (threadIdx.x == 255) bsum[blockIdx.x] = buf[255];
}

__global__ __launch_bounds__(256) void scan2_kernel(
    int* __restrict__ bsum, int* __restrict__ boff, int nblk)
{
    __shared__ int buf[256];
    int v = (threadIdx.x < nblk) ? bsum[threadIdx.x] : 0;
    buf[threadIdx.x] = v;
    __syncthreads();
#pragma unroll
    for (int off = 1; off < 256; off <<= 1) {
        int t = (threadIdx.x >= off) ? buf[threadIdx.x - off] : 0;
        __syncthreads();
        buf[threadIdx.x] += t;
        __syncthreads();
    }
    if (threadIdx.x < nblk) boff[threadIdx.x] = buf[threadIdx.x] - v;
}

// scan3: finalize rowptr, and derive per-group bucket cursors bcur[g]=rowptr[256g]
__global__ __launch_bounds__(256) void scan3_kernel(
    int* __restrict__ rowptr, const int* __restrict__ boff,
    int* __restrict__ bcur, int n)
{
    int i = blockIdx.x * 256 + threadIdx.x;
    if (i < n) {
        int v = rowptr[i] + boff[blockIdx.x];
        rowptr[i] = v;
        if ((i & 255) == 0) bcur[i >> 8] = v;
    }
    if (i == 0) rowptr[n] = NEDGES;
    if (blockIdx.x == 0 && threadIdx.x >= NGROUPS && threadIdx.x < 256)
        bcur[threadIdx.x] = NEDGES;
}

// ---------------------------------------------------------------------------
// Sort pass 1: bin edges by row>>8 into contiguous per-bucket streams.
// Record: {payload = col | w_bf16<<16, rlow = row & 255}  (8B).
// Per (block,bucket) ONE global atomic; stores per bucket are contiguous.
// ---------------------------------------------------------------------------
__global__ __launch_bounds__(256) void sort_pass1_kernel(
    const int* __restrict__ row, const int* __restrict__ col,
    const float* __restrict__ ew, int* __restrict__ bcur,
    uint2* __restrict__ inter, int nedges)
{
    __shared__ int cnt[256];
    __shared__ int base[256];
    cnt[threadIdx.x] = 0;
    __syncthreads();
    const int estart = blockIdx.x * 4096;
    const int eend = min(estart + 4096, nedges);
    for (int e = estart + threadIdx.x; e < eend; e += 256)
        atomicAdd(&cnt[row[e] >> 8], 1);
    __syncthreads();
    base[threadIdx.x] = atomicAdd(&bcur[threadIdx.x], cnt[threadIdx.x]);
    __syncthreads();
    cnt[threadIdx.x] = 0;   // reuse as rank
    __syncthreads();
    for (int e = estart + threadIdx.x; e < eend; e += 256) {
        int r = row[e];
        int b = r >> 8;
        int k = atomicAdd(&cnt[b], 1);
        unsigned payload = (unsigned)col[e] | ((unsigned)f2bf(ew[e]) << 16);
        inter[base[b] + k] = make_uint2(payload, (unsigned)(r & 255));
    }
}

// ---------------------------------------------------------------------------
// Sort pass 2: one block per 256-row group. Contiguous read of the group's
// records; scatter into the group's 16KB cedge window via LDS row cursors
// -> window stays hot in one CU's cache, writeback ~= payload size.
// ---------------------------------------------------------------------------
__global__ __launch_bounds__(256) void sort_pass2_kernel(
    const int* __restrict__ rowptr, const uint2* __restrict__ inter,
    unsigned* __restrict__ cedge, int n)
{
    __shared__ int cur[256];
    const int rows0 = blockIdx.x * 256;
    const int nrows = min(256, n - rows0);
    if (threadIdx.x < nrows) cur[threadIdx.x] = rowptr[rows0 + threadIdx.x];
    __syncthreads();
    const int jbeg = rowptr[rows0];
    const int jend = rowptr[rows0 + nrows];
    for (int j = jbeg + threadIdx.x; j < jend; j += 256) {
        uint2 rec = inter[j];
        int p = atomicAdd(&cur[rec.y], 1);
        cedge[p] = rec.x;
    }
}

// ---------------------------------------------------------------------------
// CSR gather: one wave per node, two 32-lane halves walk even/odd edges of
// the SAME node. Lane owns 4 bf16 cols (8B load). x4 unroll -> 8 row-reads
// in flight per wave. Combine via shfl_xor(32).
// ---------------------------------------------------------------------------
__global__ __launch_bounds__(256) void spmm_gather16_kernel(
    const uint2* __restrict__ h2, const int* __restrict__ rowptr,
    const unsigned* __restrict__ ce, uint2* __restrict__ agg2, int n)
{
    int node = blockIdx.x * 4 + (threadIdx.x >> 6);
    if (node >= n) return;
    const int lane = threadIdx.x & 63;
    const int half = lane >> 5;
    const int l32  = lane & 31;
    const int beg = rowptr[node];
    const int end = rowptr[node + 1];

    float a0 = 0.f, a1 = 0.f, a2 = 0.f, a3 = 0.f;
    int j = beg + half;
    for (; j + 6 < end; j += 8) {
        unsigned e0 = ce[j], e1 = ce[j+2], e2 = ce[j+4], e3 = ce[j+6];
        uint2 v0 = h2[(size_t)(e0 & 0xFFFFu) * 32 + l32];
        uint2 v1 = h2[(size_t)(e1 & 0xFFFFu) * 32 + l32];
        uint2 v2 = h2[(size_t)(e2 & 0xFFFFu) * 32 + l32];
        uint2 v3 = h2[(size_t)(e3 & 0xFFFFu) * 32 + l32];
        float w0 = bf2f((unsigned short)(e0 >> 16));
        float w1 = bf2f((unsigned short)(e1 >> 16));
        float w2 = bf2f((unsigned short)(e2 >> 16));
        float w3 = bf2f((unsigned short)(e3 >> 16));
        a0 += w0*lo_bf(v0.x) + w1*lo_bf(v1.x) + w2*lo_bf(v2.x) + w3*lo_bf(v3.x);
        a1 += w0*hi_bf(v0.x) + w1*hi_bf(v1.x) + w2*hi_bf(v2.x) + w3*hi_bf(v3.x);
        a2 += w0*lo_bf(v0.y) + w1*lo_bf(v1.y) + w2*lo_bf(v2.y) + w3*lo_bf(v3.y);
        a3 += w0*hi_bf(v0.y) + w1*hi_bf(v1.y) + w2*hi_bf(v2.y) + w3*hi_bf(v3.y);
    }
    for (; j < end; j += 2) {
        unsigned e = ce[j];
        uint2 v = h2[(size_t)(e & 0xFFFFu) * 32 + l32];
        float w = bf2f((unsigned short)(e >> 16));
        a0 += w * lo_bf(v.x); a1 += w * hi_bf(v.x);
        a2 += w * lo_bf(v.y); a3 += w * hi_bf(v.y);
    }
    a0 += __shfl_xor(a0, 32);
    a1 += __shfl_xor(a1, 32);
    a2 += __shfl_xor(a2, 32);
    a3 += __shfl_xor(a3, 32);
    if (half == 0)
        agg2[(size_t)node * 32 + l32] = make_uint2(packbf(a0, a1), packbf(a2, a3));
}

// ---------------------------------------------------------------------------
// MFMA GEMM: C = [agg|h](N x 256) @ [W;SW](256 x 128), then BN+relu+residual.
// Block: 256 thr (4 waves), BM=64 rows. Wave w owns cols [32w, 32w+32).
// A staged in LDS (bf16, XOR chunk-swizzle); B prefetched from frag-ordered Wf.
// Residual h row read back from the LDS tile. h16 updated in-place (each
// block writes only rows it staged). Last layer also writes f32 out.
// ---------------------------------------------------------------------------
__global__ __launch_bounds__(256) void gemm_mfma_kernel(
    unsigned short* __restrict__ h16,
    const unsigned short* __restrict__ agg16,
    const unsigned short* __restrict__ Wf,
    const float* __restrict__ bl, const float* __restrict__ gammal,
    const float* __restrict__ betal, const float* __restrict__ rmeanl,
    const float* __restrict__ rvarl,
    float* __restrict__ outf, int n, int write_f32)
{
    __shared__ __align__(16) unsigned short As[64 * 256];   // 32 KB
    const int tid  = threadIdx.x;
    const int lane = tid & 63;
    const int wid  = tid >> 6;
    const int brow = blockIdx.x * 64;

    bf16x8 bfr[8][2];
#pragma unroll
    for (int ks = 0; ks < 8; ++ks)
#pragma unroll
        for (int nt2 = 0; nt2 < 2; ++nt2) {
            int nt = wid * 2 + nt2;
            bfr[ks][nt2] = *(const bf16x8*)(Wf + ((size_t)(ks * 8 + nt) * 64 + lane) * 8);
        }

#pragma unroll
    for (int it = 0; it < 8; ++it) {
        int id = tid + it * 256;
        int r  = id >> 5;
        int kc = id & 31;
        int grow = brow + r;
        uint4 v = make_uint4(0, 0, 0, 0);
        if (grow < n) {
            const unsigned short* src = (kc < 16)
                ? (agg16 + (size_t)grow * DD + kc * 8)
                : (h16   + (size_t)grow * DD + (kc - 16) * 8);
            v = *(const uint4*)src;
        }
        int kcs = kc ^ (r & 7);
        *(uint4*)(&As[r * 256 + kcs * 8]) = v;
    }
    __syncthreads();

    f32x4 acc[4][2];
#pragma unroll
    for (int i = 0; i < 4; ++i)
#pragma unroll
        for (int j = 0; j < 2; ++j)
            acc[i][j] = (f32x4){0.f, 0.f, 0.f, 0.f};

#pragma unroll
    for (int ks = 0; ks < 8; ++ks) {
#pragma unroll
        for (int mt = 0; mt < 4; ++mt) {
            int m   = mt * 16 + (lane & 15);
            int kc  = ks * 4 + (lane >> 4);
            int kcs = kc ^ (m & 7);
            bf16x8 afr = *(const bf16x8*)(&As[m * 256 + kcs * 8]);
            acc[mt][0] = __builtin_amdgcn_mfma_f32_16x16x32_bf16(afr, bfr[ks][0], acc[mt][0], 0, 0, 0);
            acc[mt][1] = __builtin_amdgcn_mfma_f32_16x16x32_bf16(afr, bfr[ks][1], acc[mt][1], 0, 0, 0);
        }
    }

#pragma unroll
    for (int nt2 = 0; nt2 < 2; ++nt2) {
        const int gcol = wid * 32 + nt2 * 16 + (lane & 15);
        const float sc = gammal[gcol] * __frsqrt_rn(rvarl[gcol] + BN_EPS);
        const float sh = (bl[gcol] - rmeanl[gcol]) * sc + betal[gcol];
        const int kc_res = 16 + (gcol >> 3);
        const int ko_res = gcol & 7;
#pragma unroll
        for (int mt = 0; mt < 4; ++mt) {
#pragma unroll
            for (int r = 0; r < 4; ++r) {
                int m = mt * 16 + (lane >> 4) * 4 + r;
                int grow = brow + m;
                if (grow < n) {
                    float res = bf2f(As[m * 256 + (kc_res ^ (m & 7)) * 8 + ko_res]);
                    float t = acc[mt][nt2][r] * sc + sh;
                    float o = res + (t > 0.f ? t : 0.f);
                    h16[(size_t)grow * DD + gcol] = f2bf(o);
                    if (write_f32) outf[(size_t)grow * DD + gcol] = o;
                }
            }
        }
    }
}

extern "C" void kernel_launch(void* const* d_in, const int* in_sizes, int n_in,
                              void* d_out, int out_size, void* d_ws, size_t ws_size,
                              hipStream_t stream) {
    const float* x     = (const float*)d_in[0];
    const int*   row   = (const int*)  d_in[1];
    const int*   col   = (const int*)  d_in[2];
    const float* ew    = (const float*)d_in[3];
    const float* W     = (const float*)d_in[4];
    const float* SW    = (const float*)d_in[5];
    const float* b     = (const float*)d_in[6];
    const float* gamma = (const float*)d_in[7];
    const float* beta  = (const float*)d_in[8];
    const float* rmean = (const float*)d_in[9];
    const float* rvar  = (const float*)d_in[10];

    float* out = (float*)d_out;

    // workspace layout
    char* ws = (char*)d_ws;
    unsigned*       agg16u = (unsigned*)ws;                       // 12.8 MB
    unsigned*       h16u   = (unsigned*)(ws + 12800000);          // 12.8 MB
    unsigned short* Wf     = (unsigned short*)(ws + 25600000);    // 196608 B
    int*   rowptr = (int*)(ws + 25800000);                        // N+1 ints
    int*   deg    = (int*)(ws + 26010000);                        // N ints
    int*   bsum   = (int*)(ws + 26210016);                        // 256
    int*   boff   = (int*)(ws + 26211040);                        // 256
    int*   bcur   = (int*)(ws + 26212064);                        // 256
    unsigned* cedge = (unsigned*)(ws + 26400000);                 // 3.2 MB
    uint2*    inter = (uint2*)(ws + 29600000);                    // 6.4 MB

    // ---- build CSR once (row/col/ew are layer-invariant) ----
    hipMemsetAsync(deg, 0, NNODES * sizeof(int), stream);
    hist_convx_kernel<<<HIST_BLOCKS + 2048, 256, 0, stream>>>(
        row, deg, x, h16u, NEDGES, NNODES * 64);
    scan1_convwf_kernel<<<NBLK_SCAN + 48, 256, 0, stream>>>(
        deg, rowptr, bsum, W, SW, Wf, NNODES);
    scan2_kernel<<<1, 256, 0, stream>>>(bsum, boff, NBLK_SCAN);
    scan3_kernel<<<NBLK_SCAN, 256, 0, stream>>>(rowptr, boff, bcur, NNODES);
    sort_pass1_kernel<<<NB1, 256, 0, stream>>>(row, col, ew, bcur, inter, NEDGES);
    sort_pass2_kernel<<<NGROUPS, 256, 0, stream>>>(rowptr, inter, cedge, NNODES);

    // Only layers 0, 2, 5 are live (inner branch layers all consume the
    // branch input, so only each branch's last layer reaches the output).
    const int ggrid = (NNODES + 3) / 4;       // 12500
    const int mgrid = (NNODES + 63) / 64;     // 782

    for (int li = 0; li < 3; ++li) {
        const int l = (li == 0) ? 0 : (li == 1) ? 2 : 5;
        spmm_gather16_kernel<<<ggrid, 256, 0, stream>>>(
            (const uint2*)h16u, rowptr, cedge, (uint2*)agg16u, NNODES);
        gemm_mfma_kernel<<<mgrid, 256, 0, stream>>>(
            (unsigned short*)h16u, (const unsigned short*)agg16u,
            Wf + (size_t)li * 32768,
            b + l * DD, gamma + l * DD, beta + l * DD, rmean + l * DD, rvar + l * DD,
            out, NNODES, li == 2 ? 1 : 0);
    }
}

// Round 7
// 194.387 us; speedup vs baseline: 2.5049x; 1.1647x over previous
//
#include <hip/hip_runtime.h>

#define DD 128
#define NNODES 50000
#define NEDGES 800000
#define BN_EPS 1e-5f
#define NB1 ((NEDGES + 4095) / 4096)       // 196 edge-slice blocks
#define NGROUPS ((NNODES + 255) / 256)     // 196 row-groups (256 rows each)

typedef float f32x4 __attribute__((ext_vector_type(4)));
typedef short bf16x8 __attribute__((ext_vector_type(8)));

__device__ __forceinline__ unsigned short f2bf(float f) {
    unsigned u = __float_as_uint(f);
    u = (u + 0x7FFFu + ((u >> 16) & 1u)) >> 16;   // RNE
    return (unsigned short)u;
}
__device__ __forceinline__ float bf2f(unsigned short s) {
    return __uint_as_float((unsigned)s << 16);
}
__device__ __forceinline__ unsigned packbf(float a, float b) {
    return (unsigned)f2bf(a) | ((unsigned)f2bf(b) << 16);
}
__device__ __forceinline__ float lo_bf(unsigned u) { return __uint_as_float(u << 16); }
__device__ __forceinline__ float hi_bf(unsigned u) { return __uint_as_float(u & 0xFFFF0000u); }

// ---------------------------------------------------------------------------
// K1: per-block bucket counts (LDS histogram, NO global atomics) + x->bf16.
// pbase[b][t] = #edges in slice b with row>>8 == t.
// ---------------------------------------------------------------------------
__global__ __launch_bounds__(256) void count_convx_kernel(
    const int* __restrict__ row, int* __restrict__ pbase,
    const float* __restrict__ x, unsigned* __restrict__ h16u,
    int nedges, int npairs)
{
    const int bid = blockIdx.x;
    if (bid < NB1) {
        __shared__ int cnt[256];
        cnt[threadIdx.x] = 0;
        __syncthreads();
        const int estart = bid * 4096;
        const int eend = min(estart + 4096, nedges);
        for (int e = estart + threadIdx.x; e < eend; e += 256)
            atomicAdd(&cnt[row[e] >> 8], 1);          // LDS atomic
        __syncthreads();
        pbase[bid * 256 + threadIdx.x] = cnt[threadIdx.x];
    } else {
        int stride = (gridDim.x - NB1) * 256;
        for (int i = (bid - NB1) * 256 + threadIdx.x; i < npairs; i += stride) {
            float2 v = ((const float2*)x)[i];
            h16u[i] = packbf(v.x, v.y);
        }
    }
}

// ---------------------------------------------------------------------------
// K2: block 0: column-scan pbase in place (thread t owns bucket t across the
// 196 blocks) -> per-(block,bucket) offsets; LDS-scan bucket totals ->
// bktbase[257]; rowptr[N]=NEDGES.  Blocks 1..48: weight->fragment convert.
// Wf: [li][ks][nt][lane][i] bf16; value = B[k][n],
//     k = ks*32+(lane>>4)*8+i (k<128 -> W else SW), n = nt*16+(lane&15)
// ---------------------------------------------------------------------------
__global__ __launch_bounds__(256) void scanall_convwf_kernel(
    int* __restrict__ pbase, int* __restrict__ bktbase, int* __restrict__ rowptr,
    const float* __restrict__ W, const float* __restrict__ SW,
    unsigned short* __restrict__ Wf)
{
    if (blockIdx.x == 0) {
        __shared__ int buf[256];
        const int t = threadIdx.x;
        int s = 0;
#pragma unroll 4
        for (int blk = 0; blk < NB1; ++blk) {
            int tmp = pbase[blk * 256 + t];
            pbase[blk * 256 + t] = s;
            s += tmp;
        }
        const int v = s;                  // bucket total
        buf[t] = v;
        __syncthreads();
#pragma unroll
        for (int off = 1; off < 256; off <<= 1) {
            int tv = (t >= off) ? buf[t - off] : 0;
            __syncthreads();
            buf[t] += tv;
            __syncthreads();
        }
        bktbase[t] = buf[t] - v;          // exclusive
        if (t == 255) bktbase[256] = buf[255];
        if (t == 0) rowptr[NNODES] = NEDGES;
        return;
    }
    int t = (blockIdx.x - 1) * 256 + threadIdx.x;   // 12288 total
    if (t < 3 * 8 * 8 * 64) {
        int lane = t & 63;
        int nt   = (t >> 6) & 7;
        int ks   = (t >> 9) & 7;
        int li   = t >> 12;
        const int lmap[3] = {0, 2, 5};
        int l = lmap[li];
        int nn = nt * 16 + (lane & 15);
        unsigned short* dst = Wf + (((size_t)li * 64 + ks * 8 + nt) * 64 + lane) * 8;
#pragma unroll
        for (int i = 0; i < 8; ++i) {
            int k = ks * 32 + (lane >> 4) * 8 + i;
            float v = (k < 128) ? W[((size_t)l * 128 + k) * 128 + nn]
                                : SW[((size_t)l * 128 + (k - 128)) * 128 + nn];
            dst[i] = f2bf(v);
        }
    }
}

// ---------------------------------------------------------------------------
// K3: bin edges into contiguous per-bucket streams. Rank from LDS counters,
// base from pbase+bktbase -> ZERO global atomics.
// Record: {payload = col | w_bf16<<16, rlow = row & 255} (8B).
// ---------------------------------------------------------------------------
__global__ __launch_bounds__(256) void sort_pass1_kernel(
    const int* __restrict__ row, const int* __restrict__ col,
    const float* __restrict__ ew, const int* __restrict__ pbase,
    const int* __restrict__ bktbase, uint2* __restrict__ inter, int nedges)
{
    __shared__ int base[256];
    __shared__ int cnt[256];
    base[threadIdx.x] = pbase[blockIdx.x * 256 + threadIdx.x] + bktbase[threadIdx.x];
    cnt[threadIdx.x] = 0;
    __syncthreads();
    const int estart = blockIdx.x * 4096;
    const int eend = min(estart + 4096, nedges);
    for (int e = estart + threadIdx.x; e < eend; e += 256) {
        int r = row[e];
        int b = r >> 8;
        int k = atomicAdd(&cnt[b], 1);    // LDS atomic
        unsigned payload = (unsigned)col[e] | ((unsigned)f2bf(ew[e]) << 16);
        inter[base[b] + k] = make_uint2(payload, (unsigned)(r & 255));
    }
}

// ---------------------------------------------------------------------------
// K4: one block per 256-row group. LDS-hist rlow -> LDS scan -> rowptr for
// this group; then windowed scatter into the group's 16KB cedge slice
// (window stays hot in one CU's cache -> writeback ~= payload size).
// ---------------------------------------------------------------------------
__global__ __launch_bounds__(256) void sort_pass2_kernel(
    const int* __restrict__ bktbase, const uint2* __restrict__ inter,
    int* __restrict__ rowptr, unsigned* __restrict__ cedge, int n)
{
    __shared__ int cnt[256];
    __shared__ int cur[256];
    const int g = blockIdx.x;
    const int rows0 = g * 256;
    const int jbeg = bktbase[g];
    const int jend = bktbase[g + 1];
    cnt[threadIdx.x] = 0;
    __syncthreads();
    for (int j = jbeg + threadIdx.x; j < jend; j += 256)
        atomicAdd(&cnt[inter[j].y], 1);   // LDS atomic
    __syncthreads();
    const int v = cnt[threadIdx.x];
    __syncthreads();
#pragma unroll
    for (int off = 1; off < 256; off <<= 1) {
        int t = (threadIdx.x >= off) ? cnt[threadIdx.x - off] : 0;
        __syncthreads();
        cnt[threadIdx.x] += t;
        __syncthreads();
    }
    const int rp = jbeg + cnt[threadIdx.x] - v;   // exclusive prefix
    if (rows0 + threadIdx.x < n) rowptr[rows0 + threadIdx.x] = rp;
    cur[threadIdx.x] = rp;
    __syncthreads();
    for (int j = jbeg + threadIdx.x; j < jend; j += 256) {
        uint2 rec = inter[j];
        int p = atomicAdd(&cur[rec.y], 1);        // LDS atomic
        cedge[p] = rec.x;
    }
}

// ---------------------------------------------------------------------------
// CSR gather: one wave per node, two 32-lane halves walk even/odd edges of
// the SAME node. Lane owns 4 bf16 cols (8B load). x4 unroll -> 8 row-reads
// in flight per wave. Combine via shfl_xor(32).
// ---------------------------------------------------------------------------
__global__ __launch_bounds__(256) void spmm_gather16_kernel(
    const uint2* __restrict__ h2, const int* __restrict__ rowptr,
    const unsigned* __restrict__ ce, uint2* __restrict__ agg2, int n)
{
    int node = blockIdx.x * 4 + (threadIdx.x >> 6);
    if (node >= n) return;
    const int lane = threadIdx.x & 63;
    const int half = lane >> 5;
    const int l32  = lane & 31;
    const int beg = rowptr[node];
    const int end = rowptr[node + 1];

    float a0 = 0.f, a1 = 0.f, a2 = 0.f, a3 = 0.f;
    int j = beg + half;
    for (; j + 6 < end; j += 8) {
        unsigned e0 = ce[j], e1 = ce[j+2], e2 = ce[j+4], e3 = ce[j+6];
        uint2 v0 = h2[(size_t)(e0 & 0xFFFFu) * 32 + l32];
        uint2 v1 = h2[(size_t)(e1 & 0xFFFFu) * 32 + l32];
        uint2 v2 = h2[(size_t)(e2 & 0xFFFFu) * 32 + l32];
        uint2 v3 = h2[(size_t)(e3 & 0xFFFFu) * 32 + l32];
        float w0 = bf2f((unsigned short)(e0 >> 16));
        float w1 = bf2f((unsigned short)(e1 >> 16));
        float w2 = bf2f((unsigned short)(e2 >> 16));
        float w3 = bf2f((unsigned short)(e3 >> 16));
        a0 += w0*lo_bf(v0.x) + w1*lo_bf(v1.x) + w2*lo_bf(v2.x) + w3*lo_bf(v3.x);
        a1 += w0*hi_bf(v0.x) + w1*hi_bf(v1.x) + w2*hi_bf(v2.x) + w3*hi_bf(v3.x);
        a2 += w0*lo_bf(v0.y) + w1*lo_bf(v1.y) + w2*lo_bf(v2.y) + w3*lo_bf(v3.y);
        a3 += w0*hi_bf(v0.y) + w1*hi_bf(v1.y) + w2*hi_bf(v2.y) + w3*hi_bf(v3.y);
    }
    for (; j < end; j += 2) {
        unsigned e = ce[j];
        uint2 v = h2[(size_t)(e & 0xFFFFu) * 32 + l32];
        float w = bf2f((unsigned short)(e >> 16));
        a0 += w * lo_bf(v.x); a1 += w * hi_bf(v.x);
        a2 += w * lo_bf(v.y); a3 += w * hi_bf(v.y);
    }
    a0 += __shfl_xor(a0, 32);
    a1 += __shfl_xor(a1, 32);
    a2 += __shfl_xor(a2, 32);
    a3 += __shfl_xor(a3, 32);
    if (half == 0)
        agg2[(size_t)node * 32 + l32] = make_uint2(packbf(a0, a1), packbf(a2, a3));
}

// ---------------------------------------------------------------------------
// MFMA GEMM: C = [agg|h](N x 256) @ [W;SW](256 x 128), then BN+relu+residual.
// Block: 256 thr (4 waves), BM=64 rows. Wave w owns cols [32w, 32w+32).
// A staged in LDS (bf16, XOR chunk-swizzle); B prefetched from frag-ordered Wf.
// Residual h row read back from the LDS tile. h16 updated in-place (each
// block writes only rows it staged). Last layer also writes f32 out.
// ---------------------------------------------------------------------------
__global__ __launch_bounds__(256) void gemm_mfma_kernel(
    unsigned short* __restrict__ h16,
    const unsigned short* __restrict__ agg16,
    const unsigned short* __restrict__ Wf,
    const float* __restrict__ bl, const float* __restrict__ gammal,
    const float* __restrict__ betal, const float* __restrict__ rmeanl,
    const float* __restrict__ rvarl,
    float* __restrict__ outf, int n, int write_f32)
{
    __shared__ __align__(16) unsigned short As[64 * 256];   // 32 KB
    const int tid  = threadIdx.x;
    const int lane = tid & 63;
    const int wid  = tid >> 6;
    const int brow = blockIdx.x * 64;

    bf16x8 bfr[8][2];
#pragma unroll
    for (int ks = 0; ks < 8; ++ks)
#pragma unroll
        for (int nt2 = 0; nt2 < 2; ++nt2) {
            int nt = wid * 2 + nt2;
            bfr[ks][nt2] = *(const bf16x8*)(Wf + ((size_t)(ks * 8 + nt) * 64 + lane) * 8);
        }

#pragma unroll
    for (int it = 0; it < 8; ++it) {
        int id = tid + it * 256;
        int r  = id >> 5;
        int kc = id & 31;
        int grow = brow + r;
        uint4 v = make_uint4(0, 0, 0, 0);
        if (grow < n) {
            const unsigned short* src = (kc < 16)
                ? (agg16 + (size_t)grow * DD + kc * 8)
                : (h16   + (size_t)grow * DD + (kc - 16) * 8);
            v = *(const uint4*)src;
        }
        int kcs = kc ^ (r & 7);
        *(uint4*)(&As[r * 256 + kcs * 8]) = v;
    }
    __syncthreads();

    f32x4 acc[4][2];
#pragma unroll
    for (int i = 0; i < 4; ++i)
#pragma unroll
        for (int j = 0; j < 2; ++j)
            acc[i][j] = (f32x4){0.f, 0.f, 0.f, 0.f};

#pragma unroll
    for (int ks = 0; ks < 8; ++ks) {
#pragma unroll
        for (int mt = 0; mt < 4; ++mt) {
            int m   = mt * 16 + (lane & 15);
            int kc  = ks * 4 + (lane >> 4);
            int kcs = kc ^ (m & 7);
            bf16x8 afr = *(const bf16x8*)(&As[m * 256 + kcs * 8]);
            acc[mt][0] = __builtin_amdgcn_mfma_f32_16x16x32_bf16(afr, bfr[ks][0], acc[mt][0], 0, 0, 0);
            acc[mt][1] = __builtin_amdgcn_mfma_f32_16x16x32_bf16(afr, bfr[ks][1], acc[mt][1], 0, 0, 0);
        }
    }

#pragma unroll
    for (int nt2 = 0; nt2 < 2; ++nt2) {
        const int gcol = wid * 32 + nt2 * 16 + (lane & 15);
        const float sc = gammal[gcol] * __frsqrt_rn(rvarl[gcol] + BN_EPS);
        const float sh = (bl[gcol] - rmeanl[gcol]) * sc + betal[gcol];
        const int kc_res = 16 + (gcol >> 3);
        const int ko_res = gcol & 7;
#pragma unroll
        for (int mt = 0; mt < 4; ++mt) {
#pragma unroll
            for (int r = 0; r < 4; ++r) {
                int m = mt * 16 + (lane >> 4) * 4 + r;
                int grow = brow + m;
                if (grow < n) {
                    float res = bf2f(As[m * 256 + (kc_res ^ (m & 7)) * 8 + ko_res]);
                    float t = acc[mt][nt2][r] * sc + sh;
                    float o = res + (t > 0.f ? t : 0.f);
                    h16[(size_t)grow * DD + gcol] = f2bf(o);
                    if (write_f32) outf[(size_t)grow * DD + gcol] = o;
                }
            }
        }
    }
}

extern "C" void kernel_launch(void* const* d_in, const int* in_sizes, int n_in,
                              void* d_out, int out_size, void* d_ws, size_t ws_size,
                              hipStream_t stream) {
    const float* x     = (const float*)d_in[0];
    const int*   row   = (const int*)  d_in[1];
    const int*   col   = (const int*)  d_in[2];
    const float* ew    = (const float*)d_in[3];
    const float* W     = (const float*)d_in[4];
    const float* SW    = (const float*)d_in[5];
    const float* b     = (const float*)d_in[6];
    const float* gamma = (const float*)d_in[7];
    const float* beta  = (const float*)d_in[8];
    const float* rmean = (const float*)d_in[9];
    const float* rvar  = (const float*)d_in[10];

    float* out = (float*)d_out;

    // workspace layout
    char* ws = (char*)d_ws;
    unsigned*       agg16u = (unsigned*)ws;                       // 12.8 MB
    unsigned*       h16u   = (unsigned*)(ws + 12800000);          // 12.8 MB
    unsigned short* Wf     = (unsigned short*)(ws + 25600000);    // 196608 B
    int*   rowptr  = (int*)(ws + 25800000);                       // 50001 ints
    int*   pbase   = (int*)(ws + 26010000);                       // 196*256 ints
    int*   bktbase = (int*)(ws + 26220000);                       // 257 ints
    unsigned* cedge = (unsigned*)(ws + 26400000);                 // 3.2 MB
    uint2*    inter = (uint2*)(ws + 29600000);                    // 6.4 MB

    // ---- build CSR (zero global atomics) ----
    count_convx_kernel<<<NB1 + 2048, 256, 0, stream>>>(
        row, pbase, x, h16u, NEDGES, NNODES * 64);
    scanall_convwf_kernel<<<1 + 48, 256, 0, stream>>>(
        pbase, bktbase, rowptr, W, SW, Wf);
    sort_pass1_kernel<<<NB1, 256, 0, stream>>>(
        row, col, ew, pbase, bktbase, inter, NEDGES);
    sort_pass2_kernel<<<NGROUPS, 256, 0, stream>>>(
        bktbase, inter, rowptr, cedge, NNODES);

    // Only layers 0, 2, 5 are live (inner branch layers all consume the
    // branch input, so only each branch's last layer reaches the output).
    const int ggrid = (NNODES + 3) / 4;       // 12500
    const int mgrid = (NNODES + 63) / 64;     // 782

    for (int li = 0; li < 3; ++li) {
        const int l = (li == 0) ? 0 : (li == 1) ? 2 : 5;
        spmm_gather16_kernel<<<ggrid, 256, 0, stream>>>(
            (const uint2*)h16u, rowptr, cedge, (uint2*)agg16u, NNODES);
        gemm_mfma_kernel<<<mgrid, 256, 0, stream>>>(
            (unsigned short*)h16u, (const unsigned short*)agg16u,
            Wf + (size_t)li * 32768,
            b + l * DD, gamma + l * DD, beta + l * DD, rmean + l * DD, rvar + l * DD,
            out, NNODES, li == 2 ? 1 : 0);
    }
}

// Round 8
// 186.377 us; speedup vs baseline: 2.6125x; 1.0430x over previous
//
#include <hip/hip_runtime.h>

#define DD 128
#define NNODES 50000
#define NEDGES 800000
#define BN_EPS 1e-5f
#define NB1 ((NEDGES + 4095) / 4096)       // 196 edge-slice blocks
#define NGROUPS ((NNODES + 255) / 256)     // 196 row-groups (256 rows each)

typedef float f32x4 __attribute__((ext_vector_type(4)));
typedef short bf16x8 __attribute__((ext_vector_type(8)));

__device__ __forceinline__ unsigned short f2bf(float f) {
    unsigned u = __float_as_uint(f);
    u = (u + 0x7FFFu + ((u >> 16) & 1u)) >> 16;   // RNE
    return (unsigned short)u;
}
__device__ __forceinline__ float bf2f(unsigned short s) {
    return __uint_as_float((unsigned)s << 16);
}
__device__ __forceinline__ unsigned packbf(float a, float b) {
    return (unsigned)f2bf(a) | ((unsigned)f2bf(b) << 16);
}
__device__ __forceinline__ float lo_bf(unsigned u) { return __uint_as_float(u << 16); }
__device__ __forceinline__ float hi_bf(unsigned u) { return __uint_as_float(u & 0xFFFF0000u); }

// ---------------------------------------------------------------------------
// K1: per-block bucket counts (LDS histogram, NO global atomics) + x->bf16.
// ---------------------------------------------------------------------------
__global__ __launch_bounds__(256) void count_convx_kernel(
    const int* __restrict__ row, int* __restrict__ pbase,
    const float* __restrict__ x, unsigned* __restrict__ h16u,
    int nedges, int npairs)
{
    const int bid = blockIdx.x;
    if (bid < NB1) {
        __shared__ int cnt[256];
        cnt[threadIdx.x] = 0;
        __syncthreads();
        const int estart = bid * 4096;
        const int eend = min(estart + 4096, nedges);
        for (int e = estart + threadIdx.x; e < eend; e += 256)
            atomicAdd(&cnt[row[e] >> 8], 1);          // LDS atomic
        __syncthreads();
        pbase[bid * 256 + threadIdx.x] = cnt[threadIdx.x];
    } else {
        int stride = (gridDim.x - NB1) * 256;
        for (int i = (bid - NB1) * 256 + threadIdx.x; i < npairs; i += stride) {
            float2 v = ((const float2*)x)[i];
            h16u[i] = packbf(v.x, v.y);
        }
    }
}

// ---------------------------------------------------------------------------
// K2: block 0: column-scan pbase in place -> per-(block,bucket) offsets;
// LDS-scan bucket totals -> bktbase[257]; rowptr[N]=NEDGES.
// Blocks 1..48: weight->fragment convert.
// Wf: [li][ks][nt][lane][i] bf16; value = B[k][n],
//     k = ks*32+(lane>>4)*8+i (k<128 -> W else SW), n = nt*16+(lane&15)
// ---------------------------------------------------------------------------
__global__ __launch_bounds__(256) void scanall_convwf_kernel(
    int* __restrict__ pbase, int* __restrict__ bktbase, int* __restrict__ rowptr,
    const float* __restrict__ W, const float* __restrict__ SW,
    unsigned short* __restrict__ Wf)
{
    if (blockIdx.x == 0) {
        __shared__ int buf[256];
        const int t = threadIdx.x;
        int s = 0;
#pragma unroll 4
        for (int blk = 0; blk < NB1; ++blk) {
            int tmp = pbase[blk * 256 + t];
            pbase[blk * 256 + t] = s;
            s += tmp;
        }
        const int v = s;                  // bucket total
        buf[t] = v;
        __syncthreads();
#pragma unroll
        for (int off = 1; off < 256; off <<= 1) {
            int tv = (t >= off) ? buf[t - off] : 0;
            __syncthreads();
            buf[t] += tv;
            __syncthreads();
        }
        bktbase[t] = buf[t] - v;          // exclusive
        if (t == 255) bktbase[256] = buf[255];
        if (t == 0) rowptr[NNODES] = NEDGES;
        return;
    }
    int t = (blockIdx.x - 1) * 256 + threadIdx.x;   // 12288 total
    if (t < 3 * 8 * 8 * 64) {
        int lane = t & 63;
        int nt   = (t >> 6) & 7;
        int ks   = (t >> 9) & 7;
        int li   = t >> 12;
        const int lmap[3] = {0, 2, 5};
        int l = lmap[li];
        int nn = nt * 16 + (lane & 15);
        unsigned short* dst = Wf + (((size_t)li * 64 + ks * 8 + nt) * 64 + lane) * 8;
#pragma unroll
        for (int i = 0; i < 8; ++i) {
            int k = ks * 32 + (lane >> 4) * 8 + i;
            float v = (k < 128) ? W[((size_t)l * 128 + k) * 128 + nn]
                                : SW[((size_t)l * 128 + (k - 128)) * 128 + nn];
            dst[i] = f2bf(v);
        }
    }
}

// ---------------------------------------------------------------------------
// K3: bin edges into contiguous per-bucket streams (zero global atomics).
// Record: {payload = col | w_bf16<<16, rlow = row & 255} (8B).
// ---------------------------------------------------------------------------
__global__ __launch_bounds__(256) void sort_pass1_kernel(
    const int* __restrict__ row, const int* __restrict__ col,
    const float* __restrict__ ew, const int* __restrict__ pbase,
    const int* __restrict__ bktbase, uint2* __restrict__ inter, int nedges)
{
    __shared__ int base[256];
    __shared__ int cnt[256];
    base[threadIdx.x] = pbase[blockIdx.x * 256 + threadIdx.x] + bktbase[threadIdx.x];
    cnt[threadIdx.x] = 0;
    __syncthreads();
    const int estart = blockIdx.x * 4096;
    const int eend = min(estart + 4096, nedges);
    for (int e = estart + threadIdx.x; e < eend; e += 256) {
        int r = row[e];
        int b = r >> 8;
        int k = atomicAdd(&cnt[b], 1);    // LDS atomic
        unsigned payload = (unsigned)col[e] | ((unsigned)f2bf(ew[e]) << 16);
        inter[base[b] + k] = make_uint2(payload, (unsigned)(r & 255));
    }
}

// ---------------------------------------------------------------------------
// K4: one block per 256-row group. LDS-hist rlow -> LDS scan -> rowptr for
// this group; then windowed scatter into the group's 16KB cedge slice.
// ---------------------------------------------------------------------------
__global__ __launch_bounds__(256) void sort_pass2_kernel(
    const int* __restrict__ bktbase, const uint2* __restrict__ inter,
    int* __restrict__ rowptr, unsigned* __restrict__ cedge, int n)
{
    __shared__ int cnt[256];
    __shared__ int cur[256];
    const int g = blockIdx.x;
    const int rows0 = g * 256;
    const int jbeg = bktbase[g];
    const int jend = bktbase[g + 1];
    cnt[threadIdx.x] = 0;
    __syncthreads();
    for (int j = jbeg + threadIdx.x; j < jend; j += 256)
        atomicAdd(&cnt[inter[j].y], 1);   // LDS atomic
    __syncthreads();
    const int v = cnt[threadIdx.x];
    __syncthreads();
#pragma unroll
    for (int off = 1; off < 256; off <<= 1) {
        int t = (threadIdx.x >= off) ? cnt[threadIdx.x - off] : 0;
        __syncthreads();
        cnt[threadIdx.x] += t;
        __syncthreads();
    }
    const int rp = jbeg + cnt[threadIdx.x] - v;   // exclusive prefix
    if (rows0 + threadIdx.x < n) rowptr[rows0 + threadIdx.x] = rp;
    cur[threadIdx.x] = rp;
    __syncthreads();
    for (int j = jbeg + threadIdx.x; j < jend; j += 256) {
        uint2 rec = inter[j];
        int p = atomicAdd(&cur[rec.y], 1);        // LDS atomic
        cedge[p] = rec.x;
    }
}

// ---------------------------------------------------------------------------
// CSR gather v2: one wave per node; FOUR 16-lane quarters each walk every
// 4th edge of the node. Lane owns 8 bf16 cols (uint4, 16B load) -> a quarter
// covers the full 256B row; x4 unroll -> 16 row-reads in flight per wave.
// Combine quarters via shfl_xor(16,32); lanes 0..15 store the row (uint4).
// ---------------------------------------------------------------------------
__global__ __launch_bounds__(256) void spmm_gather16_kernel(
    const uint4* __restrict__ h4, const int* __restrict__ rowptr,
    const unsigned* __restrict__ ce, uint4* __restrict__ agg4, int n)
{
    int node = blockIdx.x * 4 + (threadIdx.x >> 6);
    if (node >= n) return;
    const int lane = threadIdx.x & 63;
    const int q    = lane >> 4;          // quarter 0..3
    const int l16  = lane & 15;
    const int beg = rowptr[node];
    const int end = rowptr[node + 1];

    float a0 = 0.f, a1 = 0.f, a2 = 0.f, a3 = 0.f;
    float a4 = 0.f, a5 = 0.f, a6 = 0.f, a7 = 0.f;

    int j = beg + q;
    for (; j + 12 < end; j += 16) {
        unsigned e0 = ce[j], e1 = ce[j+4], e2 = ce[j+8], e3 = ce[j+12];
        uint4 v0 = h4[(size_t)(e0 & 0xFFFFu) * 16 + l16];
        uint4 v1 = h4[(size_t)(e1 & 0xFFFFu) * 16 + l16];
        uint4 v2 = h4[(size_t)(e2 & 0xFFFFu) * 16 + l16];
        uint4 v3 = h4[(size_t)(e3 & 0xFFFFu) * 16 + l16];
        float w0 = bf2f((unsigned short)(e0 >> 16));
        float w1 = bf2f((unsigned short)(e1 >> 16));
        float w2 = bf2f((unsigned short)(e2 >> 16));
        float w3 = bf2f((unsigned short)(e3 >> 16));
        a0 += w0*lo_bf(v0.x) + w1*lo_bf(v1.x) + w2*lo_bf(v2.x) + w3*lo_bf(v3.x);
        a1 += w0*hi_bf(v0.x) + w1*hi_bf(v1.x) + w2*hi_bf(v2.x) + w3*hi_bf(v3.x);
        a2 += w0*lo_bf(v0.y) + w1*lo_bf(v1.y) + w2*lo_bf(v2.y) + w3*lo_bf(v3.y);
        a3 += w0*hi_bf(v0.y) + w1*hi_bf(v1.y) + w2*hi_bf(v2.y) + w3*hi_bf(v3.y);
        a4 += w0*lo_bf(v0.z) + w1*lo_bf(v1.z) + w2*lo_bf(v2.z) + w3*lo_bf(v3.z);
        a5 += w0*hi_bf(v0.z) + w1*hi_bf(v1.z) + w2*hi_bf(v2.z) + w3*hi_bf(v3.z);
        a6 += w0*lo_bf(v0.w) + w1*lo_bf(v1.w) + w2*lo_bf(v2.w) + w3*lo_bf(v3.w);
        a7 += w0*hi_bf(v0.w) + w1*hi_bf(v1.w) + w2*hi_bf(v2.w) + w3*hi_bf(v3.w);
    }
    for (; j < end; j += 4) {
        unsigned e = ce[j];
        uint4 v = h4[(size_t)(e & 0xFFFFu) * 16 + l16];
        float w = bf2f((unsigned short)(e >> 16));
        a0 += w * lo_bf(v.x); a1 += w * hi_bf(v.x);
        a2 += w * lo_bf(v.y); a3 += w * hi_bf(v.y);
        a4 += w * lo_bf(v.z); a5 += w * hi_bf(v.z);
        a6 += w * lo_bf(v.w); a7 += w * hi_bf(v.w);
    }
#pragma unroll
    for (int off = 16; off <= 32; off <<= 1) {
        a0 += __shfl_xor(a0, off); a1 += __shfl_xor(a1, off);
        a2 += __shfl_xor(a2, off); a3 += __shfl_xor(a3, off);
        a4 += __shfl_xor(a4, off); a5 += __shfl_xor(a5, off);
        a6 += __shfl_xor(a6, off); a7 += __shfl_xor(a7, off);
    }
    if (q == 0)
        agg4[(size_t)node * 16 + l16] =
            make_uint4(packbf(a0, a1), packbf(a2, a3), packbf(a4, a5), packbf(a6, a7));
}

// ---------------------------------------------------------------------------
// MFMA GEMM: C = [agg|h](N x 256) @ [W;SW](256 x 128), then BN+relu+residual.
// Last layer writes only f32 out (h16 of the last layer is dead).
// ---------------------------------------------------------------------------
__global__ __launch_bounds__(256) void gemm_mfma_kernel(
    unsigned short* __restrict__ h16,
    const unsigned short* __restrict__ agg16,
    const unsigned short* __restrict__ Wf,
    const float* __restrict__ bl, const float* __restrict__ gammal,
    const float* __restrict__ betal, const float* __restrict__ rmeanl,
    const float* __restrict__ rvarl,
    float* __restrict__ outf, int n, int write_f32)
{
    __shared__ __align__(16) unsigned short As[64 * 256];   // 32 KB
    const int tid  = threadIdx.x;
    const int lane = tid & 63;
    const int wid  = tid >> 6;
    const int brow = blockIdx.x * 64;

    bf16x8 bfr[8][2];
#pragma unroll
    for (int ks = 0; ks < 8; ++ks)
#pragma unroll
        for (int nt2 = 0; nt2 < 2; ++nt2) {
            int nt = wid * 2 + nt2;
            bfr[ks][nt2] = *(const bf16x8*)(Wf + ((size_t)(ks * 8 + nt) * 64 + lane) * 8);
        }

#pragma unroll
    for (int it = 0; it < 8; ++it) {
        int id = tid + it * 256;
        int r  = id >> 5;
        int kc = id & 31;
        int grow = brow + r;
        uint4 v = make_uint4(0, 0, 0, 0);
        if (grow < n) {
            const unsigned short* src = (kc < 16)
                ? (agg16 + (size_t)grow * DD + kc * 8)
                : (h16   + (size_t)grow * DD + (kc - 16) * 8);
            v = *(const uint4*)src;
        }
        int kcs = kc ^ (r & 7);
        *(uint4*)(&As[r * 256 + kcs * 8]) = v;
    }
    __syncthreads();

    f32x4 acc[4][2];
#pragma unroll
    for (int i = 0; i < 4; ++i)
#pragma unroll
        for (int j = 0; j < 2; ++j)
            acc[i][j] = (f32x4){0.f, 0.f, 0.f, 0.f};

#pragma unroll
    for (int ks = 0; ks < 8; ++ks) {
#pragma unroll
        for (int mt = 0; mt < 4; ++mt) {
            int m   = mt * 16 + (lane & 15);
            int kc  = ks * 4 + (lane >> 4);
            int kcs = kc ^ (m & 7);
            bf16x8 afr = *(const bf16x8*)(&As[m * 256 + kcs * 8]);
            acc[mt][0] = __builtin_amdgcn_mfma_f32_16x16x32_bf16(afr, bfr[ks][0], acc[mt][0], 0, 0, 0);
            acc[mt][1] = __builtin_amdgcn_mfma_f32_16x16x32_bf16(afr, bfr[ks][1], acc[mt][1], 0, 0, 0);
        }
    }

#pragma unroll
    for (int nt2 = 0; nt2 < 2; ++nt2) {
        const int gcol = wid * 32 + nt2 * 16 + (lane & 15);
        const float sc = gammal[gcol] * __frsqrt_rn(rvarl[gcol] + BN_EPS);
        const float sh = (bl[gcol] - rmeanl[gcol]) * sc + betal[gcol];
        const int kc_res = 16 + (gcol >> 3);
        const int ko_res = gcol & 7;
#pragma unroll
        for (int mt = 0; mt < 4; ++mt) {
#pragma unroll
            for (int r = 0; r < 4; ++r) {
                int m = mt * 16 + (lane >> 4) * 4 + r;
                int grow = brow + m;
                if (grow < n) {
                    float res = bf2f(As[m * 256 + (kc_res ^ (m & 7)) * 8 + ko_res]);
                    float t = acc[mt][nt2][r] * sc + sh;
                    float o = res + (t > 0.f ? t : 0.f);
                    if (write_f32) outf[(size_t)grow * DD + gcol] = o;
                    else           h16[(size_t)grow * DD + gcol] = f2bf(o);
                }
            }
        }
    }
}

extern "C" void kernel_launch(void* const* d_in, const int* in_sizes, int n_in,
                              void* d_out, int out_size, void* d_ws, size_t ws_size,
                              hipStream_t stream) {
    const float* x     = (const float*)d_in[0];
    const int*   row   = (const int*)  d_in[1];
    const int*   col   = (const int*)  d_in[2];
    const float* ew    = (const float*)d_in[3];
    const float* W     = (const float*)d_in[4];
    const float* SW    = (const float*)d_in[5];
    const float* b     = (const float*)d_in[6];
    const float* gamma = (const float*)d_in[7];
    const float* beta  = (const float*)d_in[8];
    const float* rmean = (const float*)d_in[9];
    const float* rvar  = (const float*)d_in[10];

    float* out = (float*)d_out;

    // workspace layout
    char* ws = (char*)d_ws;
    unsigned*       agg16u = (unsigned*)ws;                       // 12.8 MB
    unsigned*       h16u   = (unsigned*)(ws + 12800000);          // 12.8 MB
    unsigned short* Wf     = (unsigned short*)(ws + 25600000);    // 196608 B
    int*   rowptr  = (int*)(ws + 25800000);                       // 50001 ints
    int*   pbase   = (int*)(ws + 26010000);                       // 196*256 ints
    int*   bktbase = (int*)(ws + 26220000);                       // 257 ints
    unsigned* cedge = (unsigned*)(ws + 26400000);                 // 3.2 MB
    uint2*    inter = (uint2*)(ws + 29600000);                    // 6.4 MB

    // ---- build CSR (zero global atomics) ----
    count_convx_kernel<<<NB1 + 2048, 256, 0, stream>>>(
        row, pbase, x, h16u, NEDGES, NNODES * 64);
    scanall_convwf_kernel<<<1 + 48, 256, 0, stream>>>(
        pbase, bktbase, rowptr, W, SW, Wf);
    sort_pass1_kernel<<<NB1, 256, 0, stream>>>(
        row, col, ew, pbase, bktbase, inter, NEDGES);
    sort_pass2_kernel<<<NGROUPS, 256, 0, stream>>>(
        bktbase, inter, rowptr, cedge, NNODES);

    // Only layers 0, 2, 5 are live (inner branch layers all consume the
    // branch input, so only each branch's last layer reaches the output).
    const int ggrid = (NNODES + 3) / 4;       // 12500
    const int mgrid = (NNODES + 63) / 64;     // 782

    for (int li = 0; li < 3; ++li) {
        const int l = (li == 0) ? 0 : (li == 1) ? 2 : 5;
        spmm_gather16_kernel<<<ggrid, 256, 0, stream>>>(
            (const uint4*)h16u, rowptr, cedge, (uint4*)agg16u, NNODES);
        gemm_mfma_kernel<<<mgrid, 256, 0, stream>>>(
            (unsigned short*)h16u, (const unsigned short*)agg16u,
            Wf + (size_t)li * 32768,
            b + l * DD, gamma + l * DD, beta + l * DD, rmean + l * DD, rvar + l * DD,
            out, NNODES, li == 2 ? 1 : 0);
    }
}